// Round 1
// baseline (605.711 us; speedup 1.0000x reference)
//
#include <hip/hip_runtime.h>
#include <math.h>

#define NUM_C 1000
#define NQ4   250      // float4 per row (1000 / 4)
#define EPSF  1e-6f

// Workspace layout (floats): [0]=sumU_term [1]=A [2]=B [3]=sumCE [4]=nP
// Harness re-poisons d_ws each call -> memsetAsync in kernel_launch.

__global__ __launch_bounds__(256, 4) void pu_main(
    const float* __restrict__ outp,
    const int*   __restrict__ labels,
    const float* __restrict__ prior,
    const int*   __restrict__ idx,
    float*       __restrict__ acc,
    int N)
{
    // indexlist mask as padded float4 in LDS: 256 float4 = 1024 floats, [1000..1023]=0
    __shared__ float4 sIdx[256];
    {
        int t = threadIdx.x;           // 0..255, one float4 each
        int c0 = t * 4;
        float4 v;
        v.x = (c0 + 0 < NUM_C) ? (float)idx[c0 + 0] : 0.f;
        v.y = (c0 + 1 < NUM_C) ? (float)idx[c0 + 1] : 0.f;
        v.z = (c0 + 2 < NUM_C) ? (float)idx[c0 + 2] : 0.f;
        v.w = (c0 + 3 < NUM_C) ? (float)idx[c0 + 3] : 0.f;
        sIdx[t] = v;
    }
    __syncthreads();

    const int lane = threadIdx.x & 63;
    const int wave = blockIdx.x * (blockDim.x >> 6) + (threadIdx.x >> 6);
    const int nw   = gridDim.x * (blockDim.x >> 6);

    float uAcc = 0.f;                                  // per-lane (unlabeled term)
    float aAcc = 0.f, bAcc = 0.f, ceAcc = 0.f, npAcc = 0.f;  // wave-uniform

    for (int row = wave; row < N; row += nw) {
        const float4* rp = (const float4*)(outp + (size_t)row * NUM_C);
        float4 v[4];
        #pragma unroll
        for (int j = 0; j < 4; ++j) {
            int q = lane + 64 * j;
            if (q < NQ4) v[j] = rp[q];
            else         v[j] = make_float4(-INFINITY, -INFINITY, -INFINITY, -INFINITY);
        }

        // row max
        float m = -INFINITY;
        #pragma unroll
        for (int j = 0; j < 4; ++j)
            m = fmaxf(m, fmaxf(fmaxf(v[j].x, v[j].y), fmaxf(v[j].z, v[j].w)));
        #pragma unroll
        for (int off = 32; off >= 1; off >>= 1)
            m = fmaxf(m, __shfl_xor(m, off));

        // sum exp(x - m)   (padding: exp(-inf) = 0)
        float z = 0.f;
        #pragma unroll
        for (int j = 0; j < 4; ++j) {
            z += __expf(v[j].x - m) + __expf(v[j].y - m)
               + __expf(v[j].z - m) + __expf(v[j].w - m);
        }
        #pragma unroll
        for (int off = 32; off >= 1; off >>= 1)
            z += __shfl_xor(z, off);

        float invz = 1.f / z;
        float logz = __logf(z);

        int lab = labels[row];                 // wave-uniform broadcast load
        if (lab < NUM_C) {
            // labeled row: CE + pu2 label-column part; term*wU == 0
            float xl = outp[(size_t)row * NUM_C + lab];   // L1 hit (row just read)
            float sl = __expf(xl - m) * invz;
            float pl = prior[lab];
            aAcc  += -__logf(1.f - sl + EPSF) * pl;
            bAcc  += pl;
            ceAcc += (m + logz - xl);
            npAcc += 1.f;
        } else {
            // unlabeled row: term = -log(1 - soft + eps) * idxf, summed
            float t = 0.f;
            #pragma unroll
            for (int j = 0; j < 4; ++j) {
                int q = lane + 64 * j;                 // always < 256
                float4 mk = sIdx[q];
                float4 x  = v[j];
                t -= __logf(1.f - __expf(x.x - m) * invz + EPSF) * mk.x;
                t -= __logf(1.f - __expf(x.y - m) * invz + EPSF) * mk.y;
                t -= __logf(1.f - __expf(x.z - m) * invz + EPSF) * mk.z;
                t -= __logf(1.f - __expf(x.w - m) * invz + EPSF) * mk.w;
            }
            uAcc += t;
        }
    }

    // wave-reduce the per-lane term sum; one atomic set per wave
    #pragma unroll
    for (int off = 32; off >= 1; off >>= 1)
        uAcc += __shfl_xor(uAcc, off);
    if (lane == 0) {
        atomicAdd(&acc[0], uAcc);
        atomicAdd(&acc[1], aAcc);
        atomicAdd(&acc[2], bAcc);
        atomicAdd(&acc[3], ceAcc);
        atomicAdd(&acc[4], npAcc);
    }
}

__global__ void pu_final(const float* __restrict__ acc,
                         const float* __restrict__ prior,
                         float* __restrict__ outv, int N)
{
    if (threadIdx.x == 0 && blockIdx.x == 0) {
        float sumPrior = 0.f;
        for (int c = 0; c < NUM_C; ++c) sumPrior += prior[c];

        float sumU  = acc[0];
        float A     = acc[1];
        float B     = acc[2];
        float sumCE = acc[3];
        float nPf   = acc[4];
        float nUf   = (float)N - nPf;

        float pu3 = sumU / fmaxf(1.f, nUf) / (float)NUM_C;

        // pu2: full [N,C] sum collapses; non-label columns contribute -log(1+eps)*prior
        float log1peps = logf(1.f + EPSF);
        float S   = A - log1peps * (nPf * sumPrior - B);
        float pu2 = -S / fmaxf(1.f, nPf);

        float PULoss    = pu3 + pu2;
        float PULossW   = PULoss * 2.0f;   // PU_W
        float crossloss = sumCE / nPf;     // nan when nP == 0 (matches torch/jax)
        float objective = isnan(crossloss) ? PULoss : (PULossW + crossloss);

        outv[0] = objective;
        outv[1] = PULossW;
        outv[2] = crossloss;
    }
}

extern "C" void kernel_launch(void* const* d_in, const int* in_sizes, int n_in,
                              void* d_out, int out_size, void* d_ws, size_t ws_size,
                              hipStream_t stream) {
    const float* outputs   = (const float*)d_in[0];
    const int*   labels    = (const int*)d_in[1];
    const float* priorlist = (const float*)d_in[2];
    const int*   indexlist = (const int*)d_in[3];
    float*       outv      = (float*)d_out;
    float*       acc       = (float*)d_ws;

    const int N = in_sizes[1];   // 65536 rows

    hipMemsetAsync(acc, 0, 5 * sizeof(float), stream);

    const int threads = 256;
    const int blocks  = 1024;    // 4096 waves -> 16 rows/wave; 4 blocks/CU
    pu_main<<<blocks, threads, 0, stream>>>(outputs, labels, priorlist, indexlist, acc, N);
    pu_final<<<1, 64, 0, stream>>>(acc, priorlist, outv, N);
}

// Round 2
// 357.593 us; speedup vs baseline: 1.6939x; 1.6939x over previous
//
#include <hip/hip_runtime.h>
#include <math.h>

#define NUM_C   1000
#define NQ4     250      // float4 per row (1000 / 4)
#define EPSF    1e-6f
#define NBLOCKS 1024     // pu_main grid; partials = NBLOCKS * 8 floats = 32 KB in d_ws

// d_ws layout: float partial[NBLOCKS][8]; slots 0..4 = {sumU, A, B, sumCE, nP}
// Every block overwrites its own slot every call -> no zero-init needed.

__global__ __launch_bounds__(256, 4) void pu_main(
    const float* __restrict__ outp,
    const int*   __restrict__ labels,
    const float* __restrict__ prior,
    const int*   __restrict__ idx,
    float*       __restrict__ partial,
    int N)
{
    // indexlist mask as padded float4 in LDS: 256 float4 = 1024 floats, [1000..1023]=0
    __shared__ float4 sIdx[256];
    __shared__ float  sAcc[4][5];
    {
        int t = threadIdx.x;           // 0..255, one float4 each
        int c0 = t * 4;
        float4 v;
        v.x = (c0 + 0 < NUM_C) ? (float)idx[c0 + 0] : 0.f;
        v.y = (c0 + 1 < NUM_C) ? (float)idx[c0 + 1] : 0.f;
        v.z = (c0 + 2 < NUM_C) ? (float)idx[c0 + 2] : 0.f;
        v.w = (c0 + 3 < NUM_C) ? (float)idx[c0 + 3] : 0.f;
        sIdx[t] = v;
    }
    __syncthreads();

    const int lane = threadIdx.x & 63;
    const int wIn  = threadIdx.x >> 6;                 // wave in block, 0..3
    const int wave = blockIdx.x * 4 + wIn;
    const int nw   = gridDim.x * 4;

    float uAcc = 0.f;                                  // per-lane (unlabeled term)
    float aAcc = 0.f, bAcc = 0.f, ceAcc = 0.f, npAcc = 0.f;  // wave-uniform

    for (int row = wave; row < N; row += nw) {
        const float4* rp = (const float4*)(outp + (size_t)row * NUM_C);
        float4 v[4];
        #pragma unroll
        for (int j = 0; j < 4; ++j) {
            int q = lane + 64 * j;
            if (q < NQ4) v[j] = rp[q];
            else         v[j] = make_float4(-INFINITY, -INFINITY, -INFINITY, -INFINITY);
        }

        // row max
        float m = -INFINITY;
        #pragma unroll
        for (int j = 0; j < 4; ++j)
            m = fmaxf(m, fmaxf(fmaxf(v[j].x, v[j].y), fmaxf(v[j].z, v[j].w)));
        #pragma unroll
        for (int off = 32; off >= 1; off >>= 1)
            m = fmaxf(m, __shfl_xor(m, off));

        // sum exp(x - m)   (padding: exp(-inf) = 0)
        float z = 0.f;
        #pragma unroll
        for (int j = 0; j < 4; ++j) {
            z += __expf(v[j].x - m) + __expf(v[j].y - m)
               + __expf(v[j].z - m) + __expf(v[j].w - m);
        }
        #pragma unroll
        for (int off = 32; off >= 1; off >>= 1)
            z += __shfl_xor(z, off);

        float invz = 1.f / z;
        float logz = __logf(z);

        int lab = labels[row];                 // wave-uniform broadcast load
        if (lab < NUM_C) {
            // labeled row: CE + pu2 label-column part; term*wU == 0
            float xl = outp[(size_t)row * NUM_C + lab];   // L1/L2 hit (row just read)
            float sl = __expf(xl - m) * invz;
            float pl = prior[lab];
            aAcc  += -__logf(1.f - sl + EPSF) * pl;
            bAcc  += pl;
            ceAcc += (m + logz - xl);
            npAcc += 1.f;
        } else {
            // unlabeled row: term = -log(1 - soft + eps) * idxf, summed
            float t = 0.f;
            #pragma unroll
            for (int j = 0; j < 4; ++j) {
                int q = lane + 64 * j;                 // always < 256
                float4 mk = sIdx[q];
                float4 x  = v[j];
                t -= __logf(1.f - __expf(x.x - m) * invz + EPSF) * mk.x;
                t -= __logf(1.f - __expf(x.y - m) * invz + EPSF) * mk.y;
                t -= __logf(1.f - __expf(x.z - m) * invz + EPSF) * mk.z;
                t -= __logf(1.f - __expf(x.w - m) * invz + EPSF) * mk.w;
            }
            uAcc += t;
        }
    }

    // wave-reduce the per-lane term sum
    #pragma unroll
    for (int off = 32; off >= 1; off >>= 1)
        uAcc += __shfl_xor(uAcc, off);

    // block combine in LDS, one coalesced partial store per block — NO atomics
    if (lane == 0) {
        sAcc[wIn][0] = uAcc;
        sAcc[wIn][1] = aAcc;
        sAcc[wIn][2] = bAcc;
        sAcc[wIn][3] = ceAcc;
        sAcc[wIn][4] = npAcc;
    }
    __syncthreads();
    if (threadIdx.x < 5) {
        int t = threadIdx.x;
        float s = sAcc[0][t] + sAcc[1][t] + sAcc[2][t] + sAcc[3][t];
        partial[blockIdx.x * 8 + t] = s;
    }
}

__global__ __launch_bounds__(256) void pu_final(
    const float* __restrict__ partial,
    const float* __restrict__ prior,
    float*       __restrict__ outv, int N)
{
    __shared__ float red[4][6];
    const int t    = threadIdx.x;
    const int lane = t & 63;
    const int wIn  = t >> 6;

    // parallel prior sum
    float sp = 0.f;
    for (int c = t; c < NUM_C; c += 256) sp += prior[c];

    // parallel partial reduction
    float s0 = 0.f, s1 = 0.f, s2 = 0.f, s3 = 0.f, s4 = 0.f;
    for (int b = t; b < NBLOCKS; b += 256) {
        const float* p = partial + b * 8;
        s0 += p[0]; s1 += p[1]; s2 += p[2]; s3 += p[3]; s4 += p[4];
    }

    #pragma unroll
    for (int off = 32; off >= 1; off >>= 1) {
        s0 += __shfl_xor(s0, off);
        s1 += __shfl_xor(s1, off);
        s2 += __shfl_xor(s2, off);
        s3 += __shfl_xor(s3, off);
        s4 += __shfl_xor(s4, off);
        sp += __shfl_xor(sp, off);
    }
    if (lane == 0) {
        red[wIn][0] = s0; red[wIn][1] = s1; red[wIn][2] = s2;
        red[wIn][3] = s3; red[wIn][4] = s4; red[wIn][5] = sp;
    }
    __syncthreads();

    if (t == 0) {
        float sumU  = red[0][0] + red[1][0] + red[2][0] + red[3][0];
        float A     = red[0][1] + red[1][1] + red[2][1] + red[3][1];
        float B     = red[0][2] + red[1][2] + red[2][2] + red[3][2];
        float sumCE = red[0][3] + red[1][3] + red[2][3] + red[3][3];
        float nPf   = red[0][4] + red[1][4] + red[2][4] + red[3][4];
        float sumPrior = red[0][5] + red[1][5] + red[2][5] + red[3][5];
        float nUf   = (float)N - nPf;

        float pu3 = sumU / fmaxf(1.f, nUf) / (float)NUM_C;

        // pu2: full [N,C] sum collapses; non-label columns contribute -log(1+eps)*prior
        float log1peps = logf(1.f + EPSF);
        float S   = A - log1peps * (nPf * sumPrior - B);
        float pu2 = -S / fmaxf(1.f, nPf);

        float PULoss    = pu3 + pu2;
        float PULossW   = PULoss * 2.0f;   // PU_W
        float crossloss = sumCE / nPf;     // nan when nP == 0 (matches torch/jax)
        float objective = isnan(crossloss) ? PULoss : (PULossW + crossloss);

        outv[0] = objective;
        outv[1] = PULossW;
        outv[2] = crossloss;
    }
}

extern "C" void kernel_launch(void* const* d_in, const int* in_sizes, int n_in,
                              void* d_out, int out_size, void* d_ws, size_t ws_size,
                              hipStream_t stream) {
    const float* outputs   = (const float*)d_in[0];
    const int*   labels    = (const int*)d_in[1];
    const float* priorlist = (const float*)d_in[2];
    const int*   indexlist = (const int*)d_in[3];
    float*       outv      = (float*)d_out;
    float*       partial   = (float*)d_ws;   // NBLOCKS*8 floats = 32 KB

    const int N = in_sizes[1];   // 65536 rows

    pu_main<<<NBLOCKS, 256, 0, stream>>>(outputs, labels, priorlist, indexlist, partial, N);
    pu_final<<<1, 256, 0, stream>>>(partial, priorlist, outv, N);
}